// Round 5
// baseline (338.756 us; speedup 1.0000x reference)
//
#include <hip/hip_runtime.h>

// MoonLoss: mean((out' - tgt')^2) over [B=8388608, F=5] f32.
// Columns 1..4 circular: out' = mod(out,1); tgt' = tgt + wrap-shift toward out.
// R3 diagnosis: latency-bound (VGPR=16 -> 1 load-pair in flight, VALUBusy 16%,
// hbm 18%). Fix: register double-buffered batches of 4 chunk-pairs, static
// indices, counted vmcnt via compiler. Compute kept bit-identical.

constexpr unsigned FDIM = 5u;
constexpr unsigned NTOT = 41943040u;              // 8388608 * 5
constexpr unsigned NCHUNK = NTOT / 4u;            // 10,485,760 float4 chunks
constexpr int NBLOCKS = 2048;
constexpr int NTHREADS = 256;
constexpr unsigned STRIDE = (unsigned)NBLOCKS * NTHREADS;  // 524288
constexpr int ITERS = (int)(NCHUNK / STRIDE);     // 20, exact (no tail)
constexpr int BATCH = 4;                          // chunk-pairs per step

__device__ __forceinline__ float chunk_loss(float4 o4, float4 t4,
                                            unsigned base, float acc) {
  float o[4] = {o4.x, o4.y, o4.z, o4.w};
  float t[4] = {t4.x, t4.y, t4.z, t4.w};
#pragma unroll
  for (int j = 0; j < 4; ++j) {
    unsigned col = (base + (unsigned)j) % FDIM;   // magic-mul
    float oo = o[j];
    float tt = t[j];
    bool circ = (col != 0u);
    if (circ) oo = oo - floorf(oo);               // jnp.mod(o, 1.0)
    float d = oo - tt;
    float shift = (fabsf(d) > 0.5f) ? ((tt < oo) ? 1.0f : -1.0f) : 0.0f;
    float tw = circ ? (tt + shift) : tt;
    float diff = oo - tw;
    acc = fmaf(diff, diff, acc);
  }
  return acc;
}

__device__ __forceinline__ void load_batch(const float4* __restrict__ op,
                                           const float4* __restrict__ tp,
                                           unsigned tid, int b,
                                           float4 (&o)[BATCH], float4 (&t)[BATCH]) {
#pragma unroll
  for (int j = 0; j < BATCH; ++j) {
    unsigned c = tid + (unsigned)(b * BATCH + j) * STRIDE;
    o[j] = op[c];
    t[j] = tp[c];
  }
}

__device__ __forceinline__ float comp_batch(unsigned tid, int b,
                                            const float4 (&o)[BATCH],
                                            const float4 (&t)[BATCH], float acc) {
#pragma unroll
  for (int j = 0; j < BATCH; ++j) {
    unsigned c = tid + (unsigned)(b * BATCH + j) * STRIDE;
    acc = chunk_loss(o[j], t[j], c * 4u, acc);
  }
  return acc;
}

__global__ __launch_bounds__(NTHREADS, 4) void moonloss_partial(
    const float* __restrict__ outp,
    const float* __restrict__ tgtp,
    float* __restrict__ partial) {
  unsigned tid = blockIdx.x * (unsigned)NTHREADS + threadIdx.x;
  const float4* op = reinterpret_cast<const float4*>(outp);
  const float4* tp = reinterpret_cast<const float4*>(tgtp);

  float acc = 0.0f;
  float4 oA[BATCH], tA[BATCH], oB[BATCH], tB[BATCH];

  // 5 batches (ITERS/BATCH), explicit A/B double-buffer, all indices static.
  static_assert(ITERS == 20 && BATCH == 4, "sequence below assumes 5 batches");
  load_batch(op, tp, tid, 0, oA, tA);
  load_batch(op, tp, tid, 1, oB, tB);
  acc = comp_batch(tid, 0, oA, tA, acc);
  load_batch(op, tp, tid, 2, oA, tA);
  acc = comp_batch(tid, 1, oB, tB, acc);
  load_batch(op, tp, tid, 3, oB, tB);
  acc = comp_batch(tid, 2, oA, tA, acc);
  load_batch(op, tp, tid, 4, oA, tA);
  acc = comp_batch(tid, 3, oB, tB, acc);
  acc = comp_batch(tid, 4, oA, tA, acc);

  // wave64 shuffle reduction
#pragma unroll
  for (int off = 32; off > 0; off >>= 1) acc += __shfl_down(acc, off, 64);

  __shared__ float sacc[NTHREADS / 64];
  int wid = threadIdx.x >> 6;
  if ((threadIdx.x & 63) == 0) sacc[wid] = acc;
  __syncthreads();
  if (threadIdx.x == 0) {
    float s = 0.0f;
#pragma unroll
    for (int w = 0; w < NTHREADS / 64; ++w) s += sacc[w];
    partial[blockIdx.x] = s;  // every block writes -> ws poison overwritten
  }
}

__global__ __launch_bounds__(256) void moonloss_final(
    const float* __restrict__ partial, int n, float* __restrict__ out) {
  double acc = 0.0;
  for (int i = threadIdx.x; i < n; i += blockDim.x) acc += (double)partial[i];
  __shared__ double s[256];
  s[threadIdx.x] = acc;
  __syncthreads();
  for (int off = 128; off > 0; off >>= 1) {
    if (threadIdx.x < off) s[threadIdx.x] += s[threadIdx.x + off];
    __syncthreads();
  }
  if (threadIdx.x == 0) out[0] = (float)(s[0] / (double)NTOT);
}

extern "C" void kernel_launch(void* const* d_in, const int* in_sizes, int n_in,
                              void* d_out, int out_size, void* d_ws, size_t ws_size,
                              hipStream_t stream) {
  const float* outputs = (const float*)d_in[0];
  const float* targets = (const float*)d_in[1];
  float* out = (float*)d_out;
  float* partial = (float*)d_ws;  // NBLOCKS floats

  moonloss_partial<<<NBLOCKS, NTHREADS, 0, stream>>>(outputs, targets, partial);
  moonloss_final<<<1, 256, 0, stream>>>(partial, NBLOCKS, out);
}

// Round 11
// 333.833 us; speedup vs baseline: 1.0147x; 1.0147x over previous
//
#include <hip/hip_runtime.h>

// MoonLoss: mean((out' - tgt')^2) over [B=8388608, F=5] f32.
// Cols 1..4 circular: out'=mod(out,1); tgt'=tgt+wrap-shift toward out.
// R3/R5 diagnosis: latency/concurrency-bound. Compiler drains vmcnt(0) per
// load-pair (VGPR 16/36), ~4KB/wave in flight, 2.7 TB/s blended @ 17% HBM.
// R6 fix: async global_load_lds (16B) into wave-private LDS slots, DEPTH=4
// quad-buffered, hand-counted s_waitcnt vmcnt(N) + sched_barrier(0)
// (rule #18). No __syncthreads in the pipeline. Compute bit-identical.

constexpr unsigned FDIM = 5u;
constexpr unsigned NTOT = 41943040u;               // 8388608 * 5
constexpr unsigned NCHUNK = NTOT / 4u;             // 10,485,760 float4 chunks
constexpr int NBLOCKS = 2048;
constexpr int NTHREADS = 256;
constexpr unsigned STRIDE = (unsigned)NBLOCKS * NTHREADS;  // 524288 chunks
constexpr int ITERS = (int)(NCHUNK / STRIDE);      // 20, exact (no tail)
constexpr int DEPTH = 4;                           // tiles in flight per wave

// counted waits with literal immediates + scheduler fence (guide rule #18)
#define VMWAIT_(n) do { asm volatile("s_waitcnt vmcnt(" #n ")" ::: "memory"); \
                        __builtin_amdgcn_sched_barrier(0); } while (0)
#define VMWAIT(n) VMWAIT_(n)
#define LGWAIT()  do { asm volatile("s_waitcnt lgkmcnt(0)" ::: "memory"); \
                       __builtin_amdgcn_sched_barrier(0); } while (0)

__device__ __forceinline__ void glds16(const float4* g, float4* l) {
  __builtin_amdgcn_global_load_lds(
      (const __attribute__((address_space(1))) void*)g,
      (__attribute__((address_space(3))) void*)l, 16, 0, 0);
}

__device__ __forceinline__ float chunk_loss(float4 o4, float4 t4,
                                            unsigned base, float acc) {
  float o[4] = {o4.x, o4.y, o4.z, o4.w};
  float t[4] = {t4.x, t4.y, t4.z, t4.w};
#pragma unroll
  for (int j = 0; j < 4; ++j) {
    unsigned col = (base + (unsigned)j) % FDIM;    // magic-mul
    float oo = o[j];
    float tt = t[j];
    bool circ = (col != 0u);
    if (circ) oo = oo - floorf(oo);                // jnp.mod(o, 1.0)
    float d = oo - tt;
    float shift = (fabsf(d) > 0.5f) ? ((tt < oo) ? 1.0f : -1.0f) : 0.0f;
    float tw = circ ? (tt + shift) : tt;
    float diff = oo - tw;
    acc = fmaf(diff, diff, acc);
  }
  return acc;
}

__global__ __launch_bounds__(NTHREADS) void moonloss_partial(
    const float* __restrict__ outp,
    const float* __restrict__ tgtp,
    float* __restrict__ partial) {
  // wave-private quad-buffer: [slot][stream][thread] -> 32 KB/block
  __shared__ float4 buf[DEPTH][2][NTHREADS];

  const unsigned tid = threadIdx.x;
  const unsigned wbase = tid & ~63u;               // wave's LDS span base
  const unsigned gtid = blockIdx.x * (unsigned)NTHREADS + tid;
  const float4* gos = reinterpret_cast<const float4*>(outp) + gtid;  // per-lane
  const float4* gts = reinterpret_cast<const float4*>(tgtp) + gtid;

  float acc = 0.0f;

#define ISSUE(k) do {                                                   \
    glds16(gos + (unsigned)(k) * STRIDE, &buf[(k) % DEPTH][0][wbase]);  \
    glds16(gts + (unsigned)(k) * STRIDE, &buf[(k) % DEPTH][1][wbase]);  \
  } while (0)

  // prologue: fill the pipe (8 loads in flight per wave)
  ISSUE(0); ISSUE(1); ISSUE(2); ISSUE(3);

#define STEPK(k, vm) do {                                               \
    VMWAIT(vm);                       /* tile k landed in LDS */        \
    float4 o4 = buf[(k) % DEPTH][0][tid];                               \
    float4 t4 = buf[(k) % DEPTH][1][tid];                               \
    LGWAIT();                         /* reads done -> slot reusable */ \
    if ((k) + DEPTH < ITERS) ISSUE((k) + DEPTH);                        \
    acc = chunk_loss(o4, t4, (gtid + (unsigned)(k) * STRIDE) * 4u, acc);\
  } while (0)

  STEPK(0, 6);  STEPK(1, 6);  STEPK(2, 6);  STEPK(3, 6);  STEPK(4, 6);
  STEPK(5, 6);  STEPK(6, 6);  STEPK(7, 6);  STEPK(8, 6);  STEPK(9, 6);
  STEPK(10, 6); STEPK(11, 6); STEPK(12, 6); STEPK(13, 6); STEPK(14, 6);
  STEPK(15, 6); STEPK(16, 6); STEPK(17, 4); STEPK(18, 2); STEPK(19, 0);
  static_assert(ITERS == 20 && DEPTH == 4, "step sequence assumes 20 tiles");

  // wave64 shuffle reduction
#pragma unroll
  for (int off = 32; off > 0; off >>= 1) acc += __shfl_down(acc, off, 64);

  __shared__ float sacc[NTHREADS / 64];
  int wid = threadIdx.x >> 6;
  if ((threadIdx.x & 63) == 0) sacc[wid] = acc;
  __syncthreads();
  if (threadIdx.x == 0) {
    float s = 0.0f;
#pragma unroll
    for (int w = 0; w < NTHREADS / 64; ++w) s += sacc[w];
    partial[blockIdx.x] = s;  // every block writes -> ws poison overwritten
  }
}

__global__ __launch_bounds__(256) void moonloss_final(
    const float* __restrict__ partial, int n, float* __restrict__ out) {
  double acc = 0.0;
  for (int i = threadIdx.x; i < n; i += blockDim.x) acc += (double)partial[i];
  __shared__ double s[256];
  s[threadIdx.x] = acc;
  __syncthreads();
  for (int off = 128; off > 0; off >>= 1) {
    if (threadIdx.x < off) s[threadIdx.x] += s[threadIdx.x + off];
    __syncthreads();
  }
  if (threadIdx.x == 0) out[0] = (float)(s[0] / (double)NTOT);
}

extern "C" void kernel_launch(void* const* d_in, const int* in_sizes, int n_in,
                              void* d_out, int out_size, void* d_ws, size_t ws_size,
                              hipStream_t stream) {
  const float* outputs = (const float*)d_in[0];
  const float* targets = (const float*)d_in[1];
  float* out = (float*)d_out;
  float* partial = (float*)d_ws;  // NBLOCKS floats

  moonloss_partial<<<NBLOCKS, NTHREADS, 0, stream>>>(outputs, targets, partial);
  moonloss_final<<<1, 256, 0, stream>>>(partial, NBLOCKS, out);
}

// Round 14
// 332.611 us; speedup vs baseline: 1.0185x; 1.0037x over previous
//
#include <hip/hip_runtime.h>

// MoonLoss: mean((out' - tgt')^2) over [B=8388608, F=5] f32.
// Cols 1..4 circular: out'=mod(out,1); tgt'=tgt+wrap-shift toward out.
// R11: async global_load_lds pipeline (DEPTH=4, counted vmcnt) = 109-113us,
// blended 3.05 TB/s, HBM 19%, VALU 14% -> delivery pinned ~5 B/cyc/CU across
// 3 structures => per-CU outstanding-miss (MSHR) limit; delivery ∝ 1/latency.
// R12 probe: REVERSE traversal (tiles 19->0) so the L3-resident tail is
// consumed before the scan's own fills evict it (raises L3 fraction, lowers
// avg miss latency). Single change vs R11: PHYS(p)=19-p.

constexpr unsigned FDIM = 5u;
constexpr unsigned NTOT = 41943040u;               // 8388608 * 5
constexpr unsigned NCHUNK = NTOT / 4u;             // 10,485,760 float4 chunks
constexpr int NBLOCKS = 2048;
constexpr int NTHREADS = 256;
constexpr unsigned STRIDE = (unsigned)NBLOCKS * NTHREADS;  // 524288 chunks
constexpr int ITERS = (int)(NCHUNK / STRIDE);      // 20, exact (no tail)
constexpr int DEPTH = 4;                           // tiles in flight per wave

// counted waits with literal immediates + scheduler fence (guide rule #18)
#define VMWAIT_(n) do { asm volatile("s_waitcnt vmcnt(" #n ")" ::: "memory"); \
                        __builtin_amdgcn_sched_barrier(0); } while (0)
#define VMWAIT(n) VMWAIT_(n)
#define LGWAIT()  do { asm volatile("s_waitcnt lgkmcnt(0)" ::: "memory"); \
                       __builtin_amdgcn_sched_barrier(0); } while (0)

// physical tile for logical pipeline step p: reversed traversal
#define PHYS(p) ((unsigned)(ITERS - 1 - (p)))

__device__ __forceinline__ void glds16(const float4* g, float4* l) {
  __builtin_amdgcn_global_load_lds(
      (const __attribute__((address_space(1))) void*)g,
      (__attribute__((address_space(3))) void*)l, 16, 0, 0);
}

__device__ __forceinline__ float chunk_loss(float4 o4, float4 t4,
                                            unsigned base, float acc) {
  float o[4] = {o4.x, o4.y, o4.z, o4.w};
  float t[4] = {t4.x, t4.y, t4.z, t4.w};
#pragma unroll
  for (int j = 0; j < 4; ++j) {
    unsigned col = (base + (unsigned)j) % FDIM;    // magic-mul
    float oo = o[j];
    float tt = t[j];
    bool circ = (col != 0u);
    if (circ) oo = oo - floorf(oo);                // jnp.mod(o, 1.0)
    float d = oo - tt;
    float shift = (fabsf(d) > 0.5f) ? ((tt < oo) ? 1.0f : -1.0f) : 0.0f;
    float tw = circ ? (tt + shift) : tt;
    float diff = oo - tw;
    acc = fmaf(diff, diff, acc);
  }
  return acc;
}

__global__ __launch_bounds__(NTHREADS) void moonloss_partial(
    const float* __restrict__ outp,
    const float* __restrict__ tgtp,
    float* __restrict__ partial) {
  // wave-private quad-buffer: [slot][stream][thread] -> 32 KB/block
  __shared__ float4 buf[DEPTH][2][NTHREADS];

  const unsigned tid = threadIdx.x;
  const unsigned wbase = tid & ~63u;               // wave's LDS span base
  const unsigned gtid = blockIdx.x * (unsigned)NTHREADS + tid;
  const float4* gos = reinterpret_cast<const float4*>(outp) + gtid;  // per-lane
  const float4* gts = reinterpret_cast<const float4*>(tgtp) + gtid;

  float acc = 0.0f;

#define ISSUE(p) do {                                                      \
    glds16(gos + PHYS(p) * STRIDE, &buf[(p) % DEPTH][0][wbase]);           \
    glds16(gts + PHYS(p) * STRIDE, &buf[(p) % DEPTH][1][wbase]);           \
  } while (0)

  // prologue: fill the pipe (8 loads in flight per wave)
  ISSUE(0); ISSUE(1); ISSUE(2); ISSUE(3);

#define STEPK(p, vm) do {                                                  \
    VMWAIT(vm);                       /* step p landed in LDS */           \
    float4 o4 = buf[(p) % DEPTH][0][tid];                                  \
    float4 t4 = buf[(p) % DEPTH][1][tid];                                  \
    LGWAIT();                         /* reads done -> slot reusable */    \
    if ((p) + DEPTH < ITERS) ISSUE((p) + DEPTH);                           \
    acc = chunk_loss(o4, t4, (gtid + PHYS(p) * STRIDE) * 4u, acc);         \
  } while (0)

  STEPK(0, 6);  STEPK(1, 6);  STEPK(2, 6);  STEPK(3, 6);  STEPK(4, 6);
  STEPK(5, 6);  STEPK(6, 6);  STEPK(7, 6);  STEPK(8, 6);  STEPK(9, 6);
  STEPK(10, 6); STEPK(11, 6); STEPK(12, 6); STEPK(13, 6); STEPK(14, 6);
  STEPK(15, 6); STEPK(16, 6); STEPK(17, 4); STEPK(18, 2); STEPK(19, 0);
  static_assert(ITERS == 20 && DEPTH == 4, "step sequence assumes 20 tiles");

  // wave64 shuffle reduction
#pragma unroll
  for (int off = 32; off > 0; off >>= 1) acc += __shfl_down(acc, off, 64);

  __shared__ float sacc[NTHREADS / 64];
  int wid = threadIdx.x >> 6;
  if ((threadIdx.x & 63) == 0) sacc[wid] = acc;
  __syncthreads();
  if (threadIdx.x == 0) {
    float s = 0.0f;
#pragma unroll
    for (int w = 0; w < NTHREADS / 64; ++w) s += sacc[w];
    partial[blockIdx.x] = s;  // every block writes -> ws poison overwritten
  }
}

__global__ __launch_bounds__(256) void moonloss_final(
    const float* __restrict__ partial, int n, float* __restrict__ out) {
  double acc = 0.0;
  for (int i = threadIdx.x; i < n; i += blockDim.x) acc += (double)partial[i];
  __shared__ double s[256];
  s[threadIdx.x] = acc;
  __syncthreads();
  for (int off = 128; off > 0; off >>= 1) {
    if (threadIdx.x < off) s[threadIdx.x] += s[threadIdx.x + off];
    __syncthreads();
  }
  if (threadIdx.x == 0) out[0] = (float)(s[0] / (double)NTOT);
}

extern "C" void kernel_launch(void* const* d_in, const int* in_sizes, int n_in,
                              void* d_out, int out_size, void* d_ws, size_t ws_size,
                              hipStream_t stream) {
  const float* outputs = (const float*)d_in[0];
  const float* targets = (const float*)d_in[1];
  float* out = (float*)d_out;
  float* partial = (float*)d_ws;  // NBLOCKS floats

  moonloss_partial<<<NBLOCKS, NTHREADS, 0, stream>>>(outputs, targets, partial);
  moonloss_final<<<1, 256, 0, stream>>>(partial, NBLOCKS, out);
}